// Round 2
// baseline (574.716 us; speedup 1.0000x reference)
//
#include <hip/hip_runtime.h>
#include <hip/hip_bf16.h>

#define HIDDEN 128
#define NEDGES 800000
#define TILE_M 32
#define KDIM 384
#define NKSTEP 12                 // 384 / 32
#define NTILES (NEDGES / TILE_M)  // 25000

typedef __attribute__((ext_vector_type(8))) short short8;
typedef __attribute__((ext_vector_type(4))) float f32x4;

__device__ __forceinline__ unsigned short f2bf(float x) {
    union { __hip_bfloat16 b; unsigned short u; } c;
    c.b = __float2bfloat16(x);   // RNE; compiler can fuse pairs to v_cvt_pk_bf16_f32
    return c.u;
}

// Pack W (384x128 f32) into bf16 MFMA B-fragment order:
// frag = ks*8 + nf; lane holds col n = nf*16 + (lane&15),
// k = ks*32 + (lane>>4)*8 + i, i=0..7 contiguous (16B/lane).
__global__ void __launch_bounds__(256) pack_w_kernel(const float* __restrict__ W,
                                                     unsigned short* __restrict__ Wp) {
    int t = blockIdx.x * 256 + threadIdx.x;
    if (t >= 96 * 64) return;
    int lane = t & 63;
    int frag = t >> 6;
    int ks = frag >> 3, nf = frag & 7;
    int hi = lane >> 4, lo = lane & 15;
    short8 g;
#pragma unroll
    for (int i = 0; i < 8; ++i) {
        int k = ks * 32 + hi * 8 + i;
        int n = nf * 16 + lo;
        g[i] = (short)f2bf(W[k * HIDDEN + n]);
    }
    *(short8*)(Wp + (size_t)t * 8) = g;
}

__global__ void __launch_bounds__(256, 4) edge_gemm_kernel(
    const float* __restrict__ nef,
    const float* __restrict__ dist,
    const int*   __restrict__ srcs,
    const int*   __restrict__ dsts,
    const unsigned short* __restrict__ Wp,
    const float* __restrict__ bias,
    float*       __restrict__ out)
{
    __shared__ __align__(16) unsigned short A_lds[TILE_M * KDIM]; // 24 KiB

    const int tid  = threadIdx.x;
    const int lane = tid & 63;
    const int wid  = tid >> 6;
    const int lo   = lane & 15;
    const int hi   = lane >> 4;

    const float bv0 = bias[wid * 32 + lo];
    const float bv1 = bias[wid * 32 + 16 + lo];

    const int eg  = tid >> 3;   // edge row in tile
    const int lt  = tid & 7;    // 8 threads per edge row
    const int swz = eg & 7;
    unsigned short* ldsrow = A_lds + eg * KDIM;

    // per-wave base into packed B (frag = ks*8 + wid*2 + nf)
    const unsigned short* wbase = Wp + ((size_t)(wid * 2) * 64 + lane) * 8;

    int tile = blockIdx.x;
    const int stride = gridDim.x;
    if (tile >= NTILES) return;

    // ---- prologue: indices for tile and tile+stride, gathers for tile ----
    int e0 = tile * TILE_M + eg;
    int s_cur = srcs[e0], d_cur = dsts[e0];
    int s_nxt = 0, d_nxt = 0;
    {
        int t1 = tile + stride;
        if (t1 < NTILES) { int e1 = t1 * TILE_M + eg; s_nxt = srcs[e1]; d_nxt = dsts[e1]; }
    }

    float4 r[12];
    {
        const float4* srow = (const float4*)nef  + (size_t)s_cur * 32;
        const float4* drow = (const float4*)nef  + (size_t)d_cur * 32;
        const float4* frow = (const float4*)dist + (size_t)e0 * 32;
#pragma unroll
        for (int j = 0; j < 2; ++j) {
            int g = lt + 8 * j;
            r[0 + j * 2 + 0] = srow[2 * g];  r[0 + j * 2 + 1] = srow[2 * g + 1];
            r[4 + j * 2 + 0] = drow[2 * g];  r[4 + j * 2 + 1] = drow[2 * g + 1];
            r[8 + j * 2 + 0] = frow[2 * g];  r[8 + j * 2 + 1] = frow[2 * g + 1];
        }
    }

    while (tile < NTILES) {
        // ---- convert + write LDS (waits on r arrival; LDS free per prev sync) ----
#pragma unroll
        for (int seg = 0; seg < 3; ++seg) {
#pragma unroll
            for (int j = 0; j < 2; ++j) {
                float4 u = r[seg * 4 + j * 2];
                float4 v = r[seg * 4 + j * 2 + 1];
                int col8 = seg * 16 + lt + 8 * j;
                short8 pk;
                pk[0] = (short)f2bf(u.x); pk[1] = (short)f2bf(u.y);
                pk[2] = (short)f2bf(u.z); pk[3] = (short)f2bf(u.w);
                pk[4] = (short)f2bf(v.x); pk[5] = (short)f2bf(v.y);
                pk[6] = (short)f2bf(v.z); pk[7] = (short)f2bf(v.w);
                *(short8*)(ldsrow + (size_t)(col8 ^ swz) * 8) = pk;
            }
        }
        __syncthreads();

        // ---- issue NEXT tile's gathers into r (WAR only; latency hides under MFMA) ----
        const int t_next = tile + stride;
        if (t_next < NTILES) {
            int en = t_next * TILE_M + eg;
            const float4* srow = (const float4*)nef  + (size_t)s_nxt * 32;
            const float4* drow = (const float4*)nef  + (size_t)d_nxt * 32;
            const float4* frow = (const float4*)dist + (size_t)en * 32;
#pragma unroll
            for (int j = 0; j < 2; ++j) {
                int g = lt + 8 * j;
                r[0 + j * 2 + 0] = srow[2 * g];  r[0 + j * 2 + 1] = srow[2 * g + 1];
                r[4 + j * 2 + 0] = drow[2 * g];  r[4 + j * 2 + 1] = drow[2 * g + 1];
                r[8 + j * 2 + 0] = frow[2 * g];  r[8 + j * 2 + 1] = frow[2 * g + 1];
            }
            int t2 = t_next + stride;
            if (t2 < NTILES) { int e2 = t2 * TILE_M + eg; s_nxt = srcs[e2]; d_nxt = dsts[e2]; }
        }

        // ---- compute: B from L2 (Wp stays hot), A from LDS ----
        f32x4 acc00 = {0.f, 0.f, 0.f, 0.f};
        f32x4 acc01 = {0.f, 0.f, 0.f, 0.f};
        f32x4 acc10 = {0.f, 0.f, 0.f, 0.f};
        f32x4 acc11 = {0.f, 0.f, 0.f, 0.f};
#pragma unroll
        for (int ks = 0; ks < NKSTEP; ++ks) {
            short8 b0 = *(const short8*)(wbase + (size_t)(ks * 8) * 512);
            short8 b1 = *(const short8*)(wbase + (size_t)(ks * 8 + 1) * 512);
            const int c8 = ks * 4 + hi;
            short8 a0 = *(const short8*)(A_lds + lo * KDIM + ((c8 ^ (lo & 7)) * 8));
            short8 a1 = *(const short8*)(A_lds + (16 + lo) * KDIM + ((c8 ^ (lo & 7)) * 8));
            acc00 = __builtin_amdgcn_mfma_f32_16x16x32_bf16(a0, b0, acc00, 0, 0, 0);
            acc01 = __builtin_amdgcn_mfma_f32_16x16x32_bf16(a0, b1, acc01, 0, 0, 0);
            acc10 = __builtin_amdgcn_mfma_f32_16x16x32_bf16(a1, b0, acc10, 0, 0, 0);
            acc11 = __builtin_amdgcn_mfma_f32_16x16x32_bf16(a1, b1, acc11, 0, 0, 0);
        }
        __syncthreads();

        // ---- epilogue: +bias, relu, store (overlaps next iter's LDS writes) ----
#pragma unroll
        for (int rr = 0; rr < 4; ++rr) {
            const int row0 = tile * TILE_M + hi * 4 + rr;
            const int row1 = row0 + 16;
            const int col0 = wid * 32 + lo;
            const int col1 = col0 + 16;
            float v00 = acc00[rr] + bv0;
            float v01 = acc01[rr] + bv1;
            float v10 = acc10[rr] + bv0;
            float v11 = acc11[rr] + bv1;
            out[(size_t)row0 * HIDDEN + col0] = v00 > 0.f ? v00 : 0.f;
            out[(size_t)row0 * HIDDEN + col1] = v01 > 0.f ? v01 : 0.f;
            out[(size_t)row1 * HIDDEN + col0] = v10 > 0.f ? v10 : 0.f;
            out[(size_t)row1 * HIDDEN + col1] = v11 > 0.f ? v11 : 0.f;
        }

        tile = t_next;
    }
}

extern "C" void kernel_launch(void* const* d_in, const int* in_sizes, int n_in,
                              void* d_out, int out_size, void* d_ws, size_t ws_size,
                              hipStream_t stream) {
    const float* nef  = (const float*)d_in[0];
    const float* dist = (const float*)d_in[1];
    const int*   srcs = (const int*)d_in[2];
    const int*   dsts = (const int*)d_in[3];
    const float* W    = (const float*)d_in[4];
    const float* bias = (const float*)d_in[5];
    float* out = (float*)d_out;
    unsigned short* Wp = (unsigned short*)d_ws;

    hipLaunchKernelGGL(pack_w_kernel, dim3(24), dim3(256), 0, stream, W, Wp);
    hipLaunchKernelGGL(edge_gemm_kernel, dim3(1024), dim3(256), 0, stream,
                       nef, dist, srcs, dsts, Wp, bias, out);
}

// Round 3
// 278.352 us; speedup vs baseline: 2.0647x; 2.0647x over previous
//
#include <hip/hip_runtime.h>
#include <hip/hip_bf16.h>

#define HIDDEN 128
#define NEDGES 800000
#define TILE_M 32
#define KDIM 384
#define NKSTEP 12                 // 384 / 32
#define NTILES (NEDGES / TILE_M)  // 25000

typedef __attribute__((ext_vector_type(8))) short short8;
typedef __attribute__((ext_vector_type(4))) float f32x4;

__device__ __forceinline__ unsigned short f2bf(float x) {
    union { __hip_bfloat16 b; unsigned short u; } c;
    c.b = __float2bfloat16(x);
    return c.u;
}

// Pack W (384x128 f32) into bf16 MFMA B-fragment order:
// frag = ks*8 + nf; lane holds col n = nf*16 + (lane&15),
// k = ks*32 + (lane>>4)*8 + i, i=0..7 contiguous (16B/lane).
__global__ void __launch_bounds__(256) pack_w_kernel(const float* __restrict__ W,
                                                     unsigned short* __restrict__ Wp) {
    int t = blockIdx.x * 256 + threadIdx.x;
    if (t >= 96 * 64) return;
    int lane = t & 63;
    int frag = t >> 6;
    int ks = frag >> 3, nf = frag & 7;
    int hi = lane >> 4, lo = lane & 15;
    short8 g;
#pragma unroll
    for (int i = 0; i < 8; ++i) {
        int k = ks * 32 + hi * 8 + i;
        int n = nf * 16 + lo;
        g[i] = (short)f2bf(W[k * HIDDEN + n]);
    }
    *(short8*)(Wp + (size_t)t * 8) = g;
}

// convert 2 float4 -> short8 and write to swizzled LDS granule
#define CVT8(ldsrow_, u_, v_, col8_, swz_)                                   \
    do {                                                                     \
        short8 pk;                                                           \
        pk[0] = (short)f2bf((u_).x); pk[1] = (short)f2bf((u_).y);            \
        pk[2] = (short)f2bf((u_).z); pk[3] = (short)f2bf((u_).w);            \
        pk[4] = (short)f2bf((v_).x); pk[5] = (short)f2bf((v_).y);            \
        pk[6] = (short)f2bf((v_).z); pk[7] = (short)f2bf((v_).w);            \
        *(short8*)((ldsrow_) + (size_t)(((col8_) ^ (swz_)) * 8)) = pk;       \
    } while (0)

__global__ void __launch_bounds__(256, 2) edge_gemm_kernel(
    const float* __restrict__ nef,
    const float* __restrict__ dist,
    const int*   __restrict__ srcs,
    const int*   __restrict__ dsts,
    const unsigned short* __restrict__ Wp,
    const float* __restrict__ bias,
    float*       __restrict__ out)
{
    __shared__ __align__(16) unsigned short A_lds[TILE_M * KDIM]; // 24 KiB

    const int tid  = threadIdx.x;
    const int lane = tid & 63;
    const int wid  = tid >> 6;
    const int lo   = lane & 15;
    const int hi   = lane >> 4;

    const float bv0 = bias[wid * 32 + lo];
    const float bv1 = bias[wid * 32 + 16 + lo];

    const int eg  = tid >> 3;   // edge row in tile
    const int lt  = tid & 7;    // 8 threads per edge row
    const int swz = eg & 7;
    unsigned short* ldsrow = A_lds + eg * KDIM;

    const unsigned short* wbase = Wp + ((size_t)(wid * 2) * 64 + lane) * 8;

    int tile = blockIdx.x;
    const int stride = gridDim.x;
    if (tile >= NTILES) return;

    // ---- prologue ----
    int e0 = tile * TILE_M + eg;
    int s_cur = srcs[e0], d_cur = dsts[e0];
    int s_nxt = 0, d_nxt = 0;
    {
        int t1 = tile + stride;
        if (t1 < NTILES) { int e1 = t1 * TILE_M + eg; s_nxt = srcs[e1]; d_nxt = dsts[e1]; }
    }

    // named staging registers — must never spill (rule #20)
    float4 r0, r1, r2, r3, r4, r5, r6, r7, r8, r9, r10, r11;
    {
        const float4* srow = (const float4*)nef  + (size_t)s_cur * 32;
        const float4* drow = (const float4*)nef  + (size_t)d_cur * 32;
        const float4* frow = (const float4*)dist + (size_t)e0 * 32;
        const int g0 = 2 * lt, g1 = 2 * (lt + 8);
        r0 = srow[g0]; r1 = srow[g0 + 1]; r2 = srow[g1]; r3 = srow[g1 + 1];
        r4 = drow[g0]; r5 = drow[g0 + 1]; r6 = drow[g1]; r7 = drow[g1 + 1];
        r8 = frow[g0]; r9 = frow[g0 + 1]; r10 = frow[g1]; r11 = frow[g1 + 1];
    }

    while (tile < NTILES) {
        // ---- convert + write LDS (r holds this tile's rows) ----
        CVT8(ldsrow, r0, r1, lt,          swz);
        CVT8(ldsrow, r2, r3, lt + 8,      swz);
        CVT8(ldsrow, r4, r5, 16 + lt,     swz);
        CVT8(ldsrow, r6, r7, 16 + lt + 8, swz);
        CVT8(ldsrow, r8, r9, 32 + lt,     swz);
        CVT8(ldsrow, r10, r11, 32 + lt + 8, swz);
        __syncthreads();

        // ---- issue NEXT tile's gathers (latency hides under MFMA below) ----
        const int t_next = tile + stride;
        if (t_next < NTILES) {
            int en = t_next * TILE_M + eg;
            const float4* srow = (const float4*)nef  + (size_t)s_nxt * 32;
            const float4* drow = (const float4*)nef  + (size_t)d_nxt * 32;
            const float4* frow = (const float4*)dist + (size_t)en * 32;
            const int g0 = 2 * lt, g1 = 2 * (lt + 8);
            r0 = srow[g0]; r1 = srow[g0 + 1]; r2 = srow[g1]; r3 = srow[g1 + 1];
            r4 = drow[g0]; r5 = drow[g0 + 1]; r6 = drow[g1]; r7 = drow[g1 + 1];
            r8 = frow[g0]; r9 = frow[g0 + 1]; r10 = frow[g1]; r11 = frow[g1 + 1];
            int t2 = t_next + stride;
            if (t2 < NTILES) { int e2 = t2 * TILE_M + eg; s_nxt = srcs[e2]; d_nxt = dsts[e2]; }
        }

        // ---- compute: B from L2 (Wp hot), A from LDS ----
        f32x4 acc00 = {0.f, 0.f, 0.f, 0.f};
        f32x4 acc01 = {0.f, 0.f, 0.f, 0.f};
        f32x4 acc10 = {0.f, 0.f, 0.f, 0.f};
        f32x4 acc11 = {0.f, 0.f, 0.f, 0.f};
#pragma unroll
        for (int ks = 0; ks < NKSTEP; ++ks) {
            short8 b0 = *(const short8*)(wbase + (size_t)(ks * 8) * 512);
            short8 b1 = *(const short8*)(wbase + (size_t)(ks * 8 + 1) * 512);
            const int c8 = ks * 4 + hi;
            short8 a0 = *(const short8*)(A_lds + lo * KDIM + ((c8 ^ (lo & 7)) * 8));
            short8 a1 = *(const short8*)(A_lds + (16 + lo) * KDIM + ((c8 ^ (lo & 7)) * 8));
            acc00 = __builtin_amdgcn_mfma_f32_16x16x32_bf16(a0, b0, acc00, 0, 0, 0);
            acc01 = __builtin_amdgcn_mfma_f32_16x16x32_bf16(a0, b1, acc01, 0, 0, 0);
            acc10 = __builtin_amdgcn_mfma_f32_16x16x32_bf16(a1, b0, acc10, 0, 0, 0);
            acc11 = __builtin_amdgcn_mfma_f32_16x16x32_bf16(a1, b1, acc11, 0, 0, 0);
        }
        __syncthreads();

        // ---- epilogue: +bias, relu, store (overlaps next iter's staging) ----
#pragma unroll
        for (int rr = 0; rr < 4; ++rr) {
            const int row0 = tile * TILE_M + hi * 4 + rr;
            const int row1 = row0 + 16;
            const int col0 = wid * 32 + lo;
            const int col1 = col0 + 16;
            float v00 = acc00[rr] + bv0;
            float v01 = acc01[rr] + bv1;
            float v10 = acc10[rr] + bv0;
            float v11 = acc11[rr] + bv1;
            out[(size_t)row0 * HIDDEN + col0] = v00 > 0.f ? v00 : 0.f;
            out[(size_t)row0 * HIDDEN + col1] = v01 > 0.f ? v01 : 0.f;
            out[(size_t)row1 * HIDDEN + col0] = v10 > 0.f ? v10 : 0.f;
            out[(size_t)row1 * HIDDEN + col1] = v11 > 0.f ? v11 : 0.f;
        }

        tile = t_next;
    }
}

extern "C" void kernel_launch(void* const* d_in, const int* in_sizes, int n_in,
                              void* d_out, int out_size, void* d_ws, size_t ws_size,
                              hipStream_t stream) {
    const float* nef  = (const float*)d_in[0];
    const float* dist = (const float*)d_in[1];
    const int*   srcs = (const int*)d_in[2];
    const int*   dsts = (const int*)d_in[3];
    const float* W    = (const float*)d_in[4];
    const float* bias = (const float*)d_in[5];
    float* out = (float*)d_out;
    unsigned short* Wp = (unsigned short*)d_ws;

    hipLaunchKernelGGL(pack_w_kernel, dim3(24), dim3(256), 0, stream, W, Wp);
    hipLaunchKernelGGL(edge_gemm_kernel, dim3(1024), dim3(256), 0, stream,
                       nef, dist, srcs, dsts, Wp, bias, out);
}

// Round 4
// 247.308 us; speedup vs baseline: 2.3239x; 1.1255x over previous
//
#include <hip/hip_runtime.h>
#include <hip/hip_bf16.h>

#define HIDDEN 128
#define NEDGES 800000
#define TILE_M 32
#define KDIM 384
#define NKSTEP 12                 // 384 / 32
#define NTILES (NEDGES / TILE_M)  // 25000

typedef __attribute__((ext_vector_type(8))) short short8;
typedef __attribute__((ext_vector_type(4))) float f32x4;
typedef __attribute__((ext_vector_type(4))) float f4;

__device__ __forceinline__ unsigned short f2bf(float x) {
    union { __hip_bfloat16 b; unsigned short u; } c;
    c.b = __float2bfloat16(x);
    return c.u;
}

// Pack W (384x128 f32) into bf16 MFMA B-fragment order:
// frag = ks*8 + nf; lane holds col n = nf*16 + (lane&15),
// k = ks*32 + (lane>>4)*8 + i, i=0..7 contiguous (16B/lane).
__global__ void __launch_bounds__(256) pack_w_kernel(const float* __restrict__ W,
                                                     unsigned short* __restrict__ Wp) {
    int t = blockIdx.x * 256 + threadIdx.x;
    if (t >= 96 * 64) return;
    int lane = t & 63;
    int frag = t >> 6;
    int ks = frag >> 3, nf = frag & 7;
    int hi = lane >> 4, lo = lane & 15;
    short8 g;
#pragma unroll
    for (int i = 0; i < 8; ++i) {
        int k = ks * 32 + hi * 8 + i;
        int n = nf * 16 + lo;
        g[i] = (short)f2bf(W[k * HIDDEN + n]);
    }
    *(short8*)(Wp + (size_t)t * 8) = g;
}

// convert 2 f4 -> short8 and write to swizzled LDS granule
#define CVT8(ldsrow_, u_, v_, col8_, swz_)                                   \
    do {                                                                     \
        short8 pk;                                                           \
        pk[0] = (short)f2bf((u_)[0]); pk[1] = (short)f2bf((u_)[1]);          \
        pk[2] = (short)f2bf((u_)[2]); pk[3] = (short)f2bf((u_)[3]);          \
        pk[4] = (short)f2bf((v_)[0]); pk[5] = (short)f2bf((v_)[1]);          \
        pk[6] = (short)f2bf((v_)[2]); pk[7] = (short)f2bf((v_)[3]);          \
        *(short8*)((ldsrow_) + (size_t)(((col8_) ^ (swz_)) * 8)) = pk;       \
    } while (0)

__global__ void __launch_bounds__(256, 2) edge_gemm_kernel(
    const float* __restrict__ nef,
    const float* __restrict__ dist,
    const int*   __restrict__ srcs,
    const int*   __restrict__ dsts,
    const unsigned short* __restrict__ Wp,
    const float* __restrict__ bias,
    float*       __restrict__ out)
{
    __shared__ __align__(16) unsigned short A_lds[2][TILE_M * KDIM]; // 2 x 24 KiB

    const int tid  = threadIdx.x;
    const int lane = tid & 63;
    const int wid  = tid >> 6;
    const int lo   = lane & 15;
    const int hi   = lane >> 4;

    const float bv0 = bias[wid * 32 + lo];
    const float bv1 = bias[wid * 32 + 16 + lo];

    const int eg  = tid >> 3;   // edge row in tile
    const int lt  = tid & 7;    // 8 threads per edge row
    const int swz = eg & 7;

    // ---- B fragments resident for the whole kernel (96 VGPRs, fits (256,2)) ----
    short8 bfrag[NKSTEP][2];
#pragma unroll
    for (int ks = 0; ks < NKSTEP; ++ks) {
#pragma unroll
        for (int nf = 0; nf < 2; ++nf) {
            int frag = ks * 8 + wid * 2 + nf;
            bfrag[ks][nf] = *(const short8*)(Wp + ((size_t)frag * 64 + lane) * 8);
        }
    }

    int tile = blockIdx.x;
    const int stride = gridDim.x;
    if (tile >= NTILES) return;

    // ---- prologue: indices for tile, tile+stride; gathers for tile ----
    int e0 = tile * TILE_M + eg;
    int s_cur = srcs[e0], d_cur = dsts[e0];
    int s_nxt = 0, d_nxt = 0;
    {
        int t1 = tile + stride;
        if (t1 < NTILES) { int e1 = t1 * TILE_M + eg; s_nxt = srcs[e1]; d_nxt = dsts[e1]; }
    }

    // named staging registers — must never spill (rule #20)
    f4 r0, r1, r2, r3, r4, r5, r6, r7, r8, r9, r10, r11;
    {
        const f4* srow = (const f4*)nef  + (size_t)s_cur * 32;
        const f4* drow = (const f4*)nef  + (size_t)d_cur * 32;
        const f4* frow = (const f4*)dist + (size_t)e0 * 32;
        const int g0 = 2 * lt, g1 = 2 * (lt + 8);
        r0 = srow[g0]; r1 = srow[g0 + 1]; r2 = srow[g1]; r3 = srow[g1 + 1];
        r4 = drow[g0]; r5 = drow[g0 + 1]; r6 = drow[g1]; r7 = drow[g1 + 1];
        r8  = __builtin_nontemporal_load(frow + g0);
        r9  = __builtin_nontemporal_load(frow + g0 + 1);
        r10 = __builtin_nontemporal_load(frow + g1);
        r11 = __builtin_nontemporal_load(frow + g1 + 1);
    }

    int p = 0;
    while (tile < NTILES) {
        // ---- convert + write LDS buf[p] (waits on r arrival here) ----
        unsigned short* ldsrow = A_lds[p] + eg * KDIM;
        CVT8(ldsrow, r0, r1, lt,            swz);
        CVT8(ldsrow, r2, r3, lt + 8,        swz);
        CVT8(ldsrow, r4, r5, 16 + lt,       swz);
        CVT8(ldsrow, r6, r7, 16 + lt + 8,   swz);
        CVT8(ldsrow, r8, r9, 32 + lt,       swz);
        CVT8(ldsrow, r10, r11, 32 + lt + 8, swz);

        // single barrier per tile: makes buf[p] visible; protects buf[p^1]
        // (waves are <=1 barrier apart -> write buf[p^1] vs read buf[p] is safe)
        __syncthreads();

        // ---- issue NEXT tile's gathers AFTER the barrier: they stay in
        // flight across MFMA + epilogue, waited only at next convert ----
        const int t_next = tile + stride;
        if (t_next < NTILES) {
            int en = t_next * TILE_M + eg;
            const f4* srow = (const f4*)nef  + (size_t)s_nxt * 32;
            const f4* drow = (const f4*)nef  + (size_t)d_nxt * 32;
            const f4* frow = (const f4*)dist + (size_t)en * 32;
            const int g0 = 2 * lt, g1 = 2 * (lt + 8);
            r0 = srow[g0]; r1 = srow[g0 + 1]; r2 = srow[g1]; r3 = srow[g1 + 1];
            r4 = drow[g0]; r5 = drow[g0 + 1]; r6 = drow[g1]; r7 = drow[g1 + 1];
            r8  = __builtin_nontemporal_load(frow + g0);
            r9  = __builtin_nontemporal_load(frow + g0 + 1);
            r10 = __builtin_nontemporal_load(frow + g1);
            r11 = __builtin_nontemporal_load(frow + g1 + 1);
            int t2 = t_next + stride;
            if (t2 < NTILES) { int e2 = t2 * TILE_M + eg; s_nxt = srcs[e2]; d_nxt = dsts[e2]; }
        }

        // ---- compute: A from LDS buf[p], B from registers (no VMEM) ----
        f32x4 acc00 = {0.f, 0.f, 0.f, 0.f};
        f32x4 acc01 = {0.f, 0.f, 0.f, 0.f};
        f32x4 acc10 = {0.f, 0.f, 0.f, 0.f};
        f32x4 acc11 = {0.f, 0.f, 0.f, 0.f};
        const unsigned short* abase = A_lds[p];
#pragma unroll
        for (int ks = 0; ks < NKSTEP; ++ks) {
            const int c8 = ks * 4 + hi;
            short8 a0 = *(const short8*)(abase + lo * KDIM + ((c8 ^ (lo & 7)) * 8));
            short8 a1 = *(const short8*)(abase + (16 + lo) * KDIM + ((c8 ^ (lo & 7)) * 8));
            acc00 = __builtin_amdgcn_mfma_f32_16x16x32_bf16(a0, bfrag[ks][0], acc00, 0, 0, 0);
            acc01 = __builtin_amdgcn_mfma_f32_16x16x32_bf16(a0, bfrag[ks][1], acc01, 0, 0, 0);
            acc10 = __builtin_amdgcn_mfma_f32_16x16x32_bf16(a1, bfrag[ks][0], acc10, 0, 0, 0);
            acc11 = __builtin_amdgcn_mfma_f32_16x16x32_bf16(a1, bfrag[ks][1], acc11, 0, 0, 0);
        }

        // ---- epilogue: +bias, relu, nt store (never re-read) ----
#pragma unroll
        for (int rr = 0; rr < 4; ++rr) {
            const int row0 = tile * TILE_M + hi * 4 + rr;
            const int row1 = row0 + 16;
            const int col0 = wid * 32 + lo;
            const int col1 = col0 + 16;
            float v00 = acc00[rr] + bv0;
            float v01 = acc01[rr] + bv1;
            float v10 = acc10[rr] + bv0;
            float v11 = acc11[rr] + bv1;
            __builtin_nontemporal_store(v00 > 0.f ? v00 : 0.f, &out[(size_t)row0 * HIDDEN + col0]);
            __builtin_nontemporal_store(v01 > 0.f ? v01 : 0.f, &out[(size_t)row0 * HIDDEN + col1]);
            __builtin_nontemporal_store(v10 > 0.f ? v10 : 0.f, &out[(size_t)row1 * HIDDEN + col0]);
            __builtin_nontemporal_store(v11 > 0.f ? v11 : 0.f, &out[(size_t)row1 * HIDDEN + col1]);
        }

        tile = t_next;
        p ^= 1;
    }
}

extern "C" void kernel_launch(void* const* d_in, const int* in_sizes, int n_in,
                              void* d_out, int out_size, void* d_ws, size_t ws_size,
                              hipStream_t stream) {
    const float* nef  = (const float*)d_in[0];
    const float* dist = (const float*)d_in[1];
    const int*   srcs = (const int*)d_in[2];
    const int*   dsts = (const int*)d_in[3];
    const float* W    = (const float*)d_in[4];
    const float* bias = (const float*)d_in[5];
    float* out = (float*)d_out;
    unsigned short* Wp = (unsigned short*)d_ws;

    hipLaunchKernelGGL(pack_w_kernel, dim3(24), dim3(256), 0, stream, W, Wp);
    hipLaunchKernelGGL(edge_gemm_kernel, dim3(512), dim3(256), 0, stream,
                       nef, dist, srcs, dsts, Wp, bias, out);
}